// Round 1
// baseline (30122.092 us; speedup 1.0000x reference)
//
#include <hip/hip_runtime.h>
#include <math.h>

// IDE state-space Kalman filter, MI355X (gfx950).
// One workgroup per batch (16 blocks x 256 threads), full 127-step scan inside
// one kernel. P and W(=A/L/Linv) live in 144KB dynamic LDS; one 64KB global
// temp per block in d_ws. fp32 throughout (round 1: correctness anchor).

#define SQ 64
#define DQ 128
#define TQ 128
#define BQ 16
#define LDP 132           // padded LDS row stride (floats), 16B-aligned rows
#define NTH 256
#define LOG2PI 1.8378770664093454f

#define SMEM_FLOATS 36896 // see layout in kernel

__device__ __forceinline__ float block_reduce_sum(float v, float* red) {
  #pragma unroll
  for (int off = 32; off > 0; off >>= 1) v += __shfl_down(v, off);
  const int tid = threadIdx.x;
  if ((tid & 63) == 0) red[tid >> 6] = v;
  __syncthreads();
  v = red[0] + red[1] + red[2] + red[3];
  __syncthreads();
  return v;
}

// Measurement update: given P (LDS), m (LDS), obs z_t, scalar r2.
// Computes nll term, m += P*Sinv*v, P = r2 * Sinv * P   (Sinv = (P+r2 I)^-1).
__device__ void kf_update(const float* __restrict__ zt, float r2,
                          float* Pm, float* Wm, float* gtmp,
                          float* mv, float* vv, float* yv, float* xv,
                          float* mdiag, float* red,
                          float* __restrict__ Tg, float& nll) {
  const int tid = threadIdx.x;
  const int lane = tid & 63;

  if (tid < DQ) vv[tid] = zt[tid] - mv[tid];
  for (int e = tid; e < DQ * LDP; e += NTH) Wm[e] = Pm[e];
  __syncthreads();
  if (tid < DQ) Wm[tid * LDP + tid] += r2;
  __syncthreads();

  // ---- blocked Cholesky (lower), NB=16 ----
  #pragma unroll 1
  for (int kb = 0; kb < 8; kb++) {
    const int b0 = kb * 16;
    // (a) 16x16 diagonal chol: wave 0, register-resident, shfl-based
    if (tid < 64) {
      float* Wd = Wm + b0 * LDP + b0;
      float a[16];
      if (lane < 16) {
        const float4* rp = (const float4*)(Wd + lane * LDP);
        float4 q0 = rp[0], q1 = rp[1], q2v = rp[2], q3 = rp[3];
        a[0]=q0.x; a[1]=q0.y; a[2]=q0.z; a[3]=q0.w;
        a[4]=q1.x; a[5]=q1.y; a[6]=q1.z; a[7]=q1.w;
        a[8]=q2v.x; a[9]=q2v.y; a[10]=q2v.z; a[11]=q2v.w;
        a[12]=q3.x; a[13]=q3.y; a[14]=q3.z; a[15]=q3.w;
      } else {
        #pragma unroll
        for (int i = 0; i < 16; i++) a[i] = 1.0f;
      }
      #pragma unroll
      for (int j = 0; j < 16; j++) {
        float dj  = __shfl(a[j], j);
        float ljj = sqrtf(dj);
        float inv = 1.0f / ljj;
        float lij = a[j] * inv;
        a[j] = (lane == j) ? ljj : lij;
        #pragma unroll
        for (int l = j + 1; l < 16; l++) {
          float llj = __shfl(a[j], l);
          a[l] = fmaf(-lij, llj, a[l]);
        }
      }
      if (lane < 16) {
        float4* rp = (float4*)(Wd + lane * LDP);
        rp[0] = make_float4(a[0], a[1], a[2], a[3]);
        rp[1] = make_float4(a[4], a[5], a[6], a[7]);
        rp[2] = make_float4(a[8], a[9], a[10], a[11]);
        rp[3] = make_float4(a[12], a[13], a[14], a[15]);
      }
    }
    __syncthreads();
    if (kb == 7) break;
    const int base = b0 + 16;
    const int nbelow = DQ - base;
    // (b) panel triangular solve: one thread per row below
    if (tid < nbelow) {
      const int r = base + tid;
      const float* Ld = Wm + b0 * LDP + b0;
      float* wrow = Wm + r * LDP + b0;
      float x[16];
      #pragma unroll
      for (int jj = 0; jj < 16; jj++) {
        float s = wrow[jj];
        #pragma unroll
        for (int l = 0; l < 16; l++) { if (l < jj) s = fmaf(-x[l], Ld[jj * LDP + l], s); }
        x[jj] = s / Ld[jj * LDP + jj];
      }
      #pragma unroll
      for (int jj = 0; jj < 16; jj++) wrow[jj] = x[jj];
    }
    __syncthreads();
    // (c) trailing update by 16x16 blocks (lower only)
    {
      const int mrow = tid >> 4, mcol = tid & 15;
      const int mb = 7 - kb;
      for (int bi = 0; bi < mb; bi++) {
        for (int bj = 0; bj <= bi; bj++) {
          if (bi > bj || mrow >= mcol) {
            const int i = base + bi * 16 + mrow;
            const int j = base + bj * 16 + mcol;
            const float* pi = Wm + i * LDP + b0;
            const float* pj = Wm + j * LDP + b0;
            float s = 0.0f;
            #pragma unroll
            for (int l = 0; l < 16; l++) s = fmaf(pi[l], pj[l], s);
            Wm[i * LDP + j] -= s;
          }
        }
      }
    }
    __syncthreads();
  }

  float ldv = (tid < DQ) ? logf(Wm[tid * LDP + tid]) : 0.0f;
  float logdet = 2.0f * block_reduce_sum(ldv, red);

  // ---- blocked inverse of L; M = L^-1 stored transposed in strict upper of
  // Wm (M[r][c] at Wm[c*LDP+r], r>c), diagonal in mdiag. L stays intact. ----
  // d=0: diagonal 16x16 blocks, one thread per (block, column)
  if (tid < DQ) {
    const int blk = tid >> 4, col = tid & 15;
    const int bb = blk * 16;
    const float* Lb = Wm + bb * LDP + bb;
    float x[16];
    #pragma unroll
    for (int i = 0; i < 16; i++) {
      float s = (i == col) ? 1.0f : 0.0f;
      #pragma unroll
      for (int k = 0; k < 16; k++) { if (k < i) s = fmaf(-Lb[i * LDP + k], x[k], s); }
      float val = s / Lb[i * LDP + i];
      x[i] = (i < col) ? 0.0f : val;
      if (i == col) mdiag[tid] = val;
      if (i > col) Wm[(bb + col) * LDP + (bb + i)] = val;
    }
  }
  __syncthreads();
  // d=1..7: M_IJ = -M_II * (sum_{K=J..I-1} L_IK M_KJ)
  #pragma unroll 1
  for (int d = 1; d < 8; d++) {
    const int i16 = tid >> 4, j16 = tid & 15;
    for (int nb = 0; nb + d < 8; nb++) {
      const int J = nb, I = nb + d;
      const float* Lrow = Wm + (I * 16 + i16) * LDP;
      // K = J (triangular M_JJ)
      float g = Lrow[J * 16 + j16] * mdiag[J * 16 + j16];
      for (int k = j16 + 1; k < 16; k++)
        g = fmaf(Lrow[J * 16 + k], Wm[(J * 16 + j16) * LDP + (J * 16 + k)], g);
      for (int K = J + 1; K < I; K++) {
        #pragma unroll
        for (int k = 0; k < 16; k++)
          g = fmaf(Lrow[K * 16 + k], Wm[(J * 16 + j16) * LDP + (K * 16 + k)], g);
      }
      gtmp[nb * 256 + tid] = g;
    }
    __syncthreads();
    for (int nb = 0; nb + d < 8; nb++) {
      const int J = nb, I = nb + d;
      const float* gb = gtmp + nb * 256;
      float s = mdiag[I * 16 + i16] * gb[i16 * 16 + j16];
      for (int k = 0; k < i16; k++)
        s = fmaf(Wm[(I * 16 + k) * LDP + (I * 16 + i16)], gb[k * 16 + j16], s);
      Wm[(J * 16 + j16) * LDP + (I * 16 + i16)] = -s;
    }
    __syncthreads();
  }

  // ---- y = M v ; quad = |y|^2 ; xv = M^T y = Sinv v ; m += P xv ----
  if (tid < DQ) {
    float s = mdiag[tid] * vv[tid];
    for (int k = 0; k < tid; k++) s = fmaf(Wm[k * LDP + tid], vv[k], s);
    yv[tid] = s;
  }
  __syncthreads();
  float qv = (tid < DQ) ? yv[tid] * yv[tid] : 0.0f;
  float quad = block_reduce_sum(qv, red);
  if (tid < DQ) {
    float s = mdiag[tid] * yv[tid];
    for (int k = tid + 1; k < DQ; k++) s = fmaf(Wm[tid * LDP + k], yv[k], s);
    xv[tid] = s;
  }
  __syncthreads();
  if (tid < DQ) {
    float s = mv[tid];
    const float* prow = Pm + tid * LDP;
    for (int c = 0; c < DQ; c++) s = fmaf(prow[c], xv[c], s);
    mv[tid] = s;
  }
  nll += 0.5f * (quad + logdet + (float)DQ * LOG2PI);

  // ---- Y = M * P  -> Tg (global temp) ----
  {
    const int cg = tid & 15, rg = tid >> 4;
    const int c0 = cg * 8, r0 = rg * 8;
    float acc[8][8];
    #pragma unroll
    for (int i = 0; i < 8; i++)
      #pragma unroll
      for (int j = 0; j < 8; j++) acc[i][j] = 0.0f;
    for (int k = 0; k < r0; k++) {
      float4 m0 = *(const float4*)&Wm[k * LDP + r0];
      float4 m1 = *(const float4*)&Wm[k * LDP + r0 + 4];
      float4 p0 = *(const float4*)&Pm[k * LDP + c0];
      float4 p1 = *(const float4*)&Pm[k * LDP + c0 + 4];
      float mm[8] = {m0.x, m0.y, m0.z, m0.w, m1.x, m1.y, m1.z, m1.w};
      float pp[8] = {p0.x, p0.y, p0.z, p0.w, p1.x, p1.y, p1.z, p1.w};
      #pragma unroll
      for (int i = 0; i < 8; i++)
        #pragma unroll
        for (int j = 0; j < 8; j++) acc[i][j] = fmaf(mm[i], pp[j], acc[i][j]);
    }
    #pragma unroll
    for (int kk = 0; kk < 8; kk++) {
      const int k = r0 + kk;
      float4 p0 = *(const float4*)&Pm[k * LDP + c0];
      float4 p1 = *(const float4*)&Pm[k * LDP + c0 + 4];
      float pp[8] = {p0.x, p0.y, p0.z, p0.w, p1.x, p1.y, p1.z, p1.w};
      #pragma unroll
      for (int i = 0; i < 8; i++) {
        float coef = (kk < i) ? Wm[k * LDP + r0 + i] : ((kk == i) ? mdiag[k] : 0.0f);
        #pragma unroll
        for (int j = 0; j < 8; j++) acc[i][j] = fmaf(coef, pp[j], acc[i][j]);
      }
    }
    #pragma unroll
    for (int i = 0; i < 8; i++) {
      *(float4*)&Tg[(r0 + i) * DQ + c0]     = make_float4(acc[i][0], acc[i][1], acc[i][2], acc[i][3]);
      *(float4*)&Tg[(r0 + i) * DQ + c0 + 4] = make_float4(acc[i][4], acc[i][5], acc[i][6], acc[i][7]);
    }
  }
  __syncthreads();

  // ---- P = r2 * (M^T * Y) ----
  {
    const int cg = tid & 15, rg = tid >> 4;
    const int c0 = cg * 8, r0 = rg * 8;
    float acc[8][8];
    #pragma unroll
    for (int i = 0; i < 8; i++)
      #pragma unroll
      for (int j = 0; j < 8; j++) acc[i][j] = 0.0f;
    #pragma unroll
    for (int kk = 0; kk < 8; kk++) {
      const int k = r0 + kk;
      float4 y0 = *(const float4*)&Tg[k * DQ + c0];
      float4 y1 = *(const float4*)&Tg[k * DQ + c0 + 4];
      float yy[8] = {y0.x, y0.y, y0.z, y0.w, y1.x, y1.y, y1.z, y1.w};
      #pragma unroll
      for (int i = 0; i < 8; i++) {
        float coef = (kk > i) ? Wm[(r0 + i) * LDP + k] : ((kk == i) ? mdiag[r0 + i] : 0.0f);
        #pragma unroll
        for (int j = 0; j < 8; j++) acc[i][j] = fmaf(coef, yy[j], acc[i][j]);
      }
    }
    for (int k = r0 + 8; k < DQ; k += 4) {
      float av[8][4];
      #pragma unroll
      for (int i = 0; i < 8; i++) {
        float4 a4 = *(const float4*)&Wm[(r0 + i) * LDP + k];
        av[i][0] = a4.x; av[i][1] = a4.y; av[i][2] = a4.z; av[i][3] = a4.w;
      }
      #pragma unroll
      for (int kk = 0; kk < 4; kk++) {
        float4 y0 = *(const float4*)&Tg[(k + kk) * DQ + c0];
        float4 y1 = *(const float4*)&Tg[(k + kk) * DQ + c0 + 4];
        float yy[8] = {y0.x, y0.y, y0.z, y0.w, y1.x, y1.y, y1.z, y1.w};
        #pragma unroll
        for (int i = 0; i < 8; i++)
          #pragma unroll
          for (int j = 0; j < 8; j++) acc[i][j] = fmaf(av[i][kk], yy[j], acc[i][j]);
      }
    }
    #pragma unroll
    for (int i = 0; i < 8; i++)
      #pragma unroll
      for (int j = 0; j < 8; j++)
        Pm[(r0 + i) * LDP + c0 + j] = r2 * acc[i][j];
  }
  __syncthreads();
}

extern "C" __global__ __launch_bounds__(NTH, 1)
void ide_kf_kernel(const float* __restrict__ z_seq,
                   const float* __restrict__ site_lon,
                   const float* __restrict__ site_lat,
                   const float* __restrict__ mu_seq,
                   const float* __restrict__ sigma_seq,
                   const float* __restrict__ log_q,
                   const float* __restrict__ log_r,
                   const float* __restrict__ log_p0,
                   const float* __restrict__ log_damp,
                   const float* __restrict__ init_mean,
                   const float* __restrict__ coupling_raw,
                   float* __restrict__ ws) {
  extern __shared__ float smem[];
  float* Pm     = smem;                  // 128*132
  float* Wm     = Pm + DQ * LDP;         // 128*132
  float* gtmp   = Wm + DQ * LDP;         // 2048
  float* coords = gtmp + 2048;           // 128
  float* mv     = coords + 128;          // 128
  float* vv     = mv + DQ;               // 128
  float* yv     = vv + DQ;               // 128
  float* xv     = yv + DQ;               // 128
  float* mdiag  = xv + DQ;               // 128
  float* rs     = mdiag + DQ;            // 256
  float* tsb    = rs + 256;              // 24
  float* red    = tsb + 24;              // 8

  const int tid = threadIdx.x;
  const int b = blockIdx.x;
  float* Tg = ws + (size_t)b * (DQ * DQ);
  float* nll_out = ws + (size_t)BQ * (DQ * DQ);

  const float r2 = expf(2.0f * log_r[0]);
  const float q2 = expf(2.0f * log_q[0]);
  const float p0sq = expf(2.0f * log_p0[0]);
  const float damping = expf(log_damp[0]);
  const float cpl00 = 1.0f + 0.25f * tanhf(coupling_raw[0]);
  const float cpl01 = 0.25f * tanhf(coupling_raw[1]);
  const float cpl10 = 0.25f * tanhf(coupling_raw[2]);
  const float cpl11 = 1.0f + 0.25f * tanhf(coupling_raw[3]);

  // ---- lon/lat projection (same for every batch; cheap, done per block) ----
  float myLon = (tid < SQ) ? site_lon[tid] : 0.0f;
  float myLat = (tid < SQ) ? site_lat[tid] : 0.0f;
  float lat0 = block_reduce_sum(myLat, red) * (1.0f / 64.0f);
  float lon0 = block_reduce_sum(myLon, red) * (1.0f / 64.0f);
  if (tid < SQ) {
    const float km = 111.32f;
    float cs = cosf(lat0 * 0.017453292519943295f);
    coords[2 * tid]     = (myLon - lon0) * (km * cs);
    coords[2 * tid + 1] = (myLat - lat0) * km;
  }
  __syncthreads();
  float dsum = 0.0f, dcnt = 0.0f;
  for (int idx = tid; idx < SQ * SQ; idx += NTH) {
    int i = idx >> 6, j = idx & 63;
    float dx = coords[2 * i] - coords[2 * j];
    float dy = coords[2 * i + 1] - coords[2 * j + 1];
    float d = sqrtf(dx * dx + dy * dy + 1e-12f);
    dsum += d;
    if (d > 1e-6f) dcnt += 1.0f;
  }
  dsum = block_reduce_sum(dsum, red);
  dcnt = block_reduce_sum(dcnt, red);
  float scale = dsum / fmaxf(dcnt, 1.0f);
  float sdiv = 1.0f / fmaxf(scale, 1e-6f);
  if (tid < SQ) { coords[2 * tid] *= sdiv; coords[2 * tid + 1] *= sdiv; }

  // ---- init m, P; first measurement update (t=0) ----
  for (int e = tid; e < DQ * LDP; e += NTH) Pm[e] = 0.0f;
  __syncthreads();
  if (tid < DQ) { Pm[tid * LDP + tid] = p0sq; mv[tid] = init_mean[tid]; }
  __syncthreads();

  float nll = 0.0f;
  kf_update(z_seq + ((size_t)b * TQ) * DQ, r2, Pm, Wm, gtmp, mv, vv, yv, xv,
            mdiag, red, Tg, nll);

  // ---- time scan ----
  #pragma unroll 1
  for (int t = 1; t < TQ; t++) {
    const float* mu_t = mu_seq + ((size_t)b * (TQ - 1) + (t - 1)) * 4;
    const float* sg_t = sigma_seq + ((size_t)b * (TQ - 1) + (t - 1)) * 16;
    const float* zt = z_seq + ((size_t)b * TQ + t) * DQ;

    // per-(t,s) Gaussian parameters
    if (tid < 4) {
      const int tt = tid >> 1, ss = tid & 1;
      float m0v = mu_t[0], m1v = mu_t[1], m2v = mu_t[2], m3v = mu_t[3];
      float dmx, dmy, c00, c01, c11;
      if (tt == 0 && ss == 0) {
        dmx = m0v; dmy = m1v;
        c00 = 0.5f * (sg_t[0] + sg_t[0]);
        c01 = 0.5f * (sg_t[1] + sg_t[4]);
        c11 = 0.5f * (sg_t[5] + sg_t[5]);
      } else if (tt == 1 && ss == 1) {
        dmx = m2v; dmy = m3v;
        c00 = 0.5f * (sg_t[10] + sg_t[10]);
        c01 = 0.5f * (sg_t[11] + sg_t[14]);
        c11 = 0.5f * (sg_t[15] + sg_t[15]);
      } else {
        dmx = 0.5f * (m0v + m2v); dmy = 0.5f * (m1v + m3v);
        float s00 = sg_t[0];
        float s02 = 0.5f * (sg_t[2] + sg_t[8]);
        float s22 = sg_t[10];
        float s01 = 0.5f * (sg_t[1] + sg_t[4]);
        float s03 = 0.5f * (sg_t[3] + sg_t[12]);
        float s21 = 0.5f * (sg_t[9] + sg_t[6]);
        float s23 = 0.5f * (sg_t[11] + sg_t[14]);
        float s11 = sg_t[5];
        float s13 = 0.5f * (sg_t[7] + sg_t[13]);
        float s33 = sg_t[15];
        c00 = 0.25f * (s00 + s02 + s02 + s22);
        c01 = 0.25f * (s01 + s03 + s21 + s23);
        c11 = 0.25f * (s11 + s13 + s13 + s33);
      }
      float D00 = 1.0001f + 2.0f * c00;
      float D01 = 2.0f * c01;
      float D11 = 1.0001f + 2.0f * c11;
      float det = D00 * D11 - D01 * D01;
      float inv = 1.0f / det;
      tsb[tid * 6 + 0] = dmx;
      tsb[tid * 6 + 1] = dmy;
      tsb[tid * 6 + 2] = D11 * inv;
      tsb[tid * 6 + 3] = -D01 * inv;
      tsb[tid * 6 + 4] = D00 * inv;
      tsb[tid * 6 + 5] = logf(det);
    }
    __syncthreads();

    // ---- build A into Wm (row-normalized kernel + coupling + damping) ----
    {
      const int r = tid >> 1, ss = tid & 1, tt = r >> 6, i = r & 63;
      const float* tp = tsb + (tt * 2 + ss) * 6;
      float dmx = tp[0], dmy = tp[1], d00 = tp[2], d01 = tp[3], d11 = tp[4], ldts = tp[5];
      float cix = coords[2 * i], ciy = coords[2 * i + 1];
      float rsum = 0.0f;
      float* wrow = Wm + r * LDP + ss * 64;
      for (int j = 0; j < SQ; j++) {
        float dx = cix - coords[2 * j] - dmx;
        float dy = ciy - coords[2 * j + 1] - dmy;
        float qf = d00 * dx * dx + 2.0f * d01 * dx * dy + d11 * dy * dy;
        float kv = expf(-0.5f * (qf + ldts));
        wrow[j] = kv;
        rsum += kv;
      }
      rs[r * 2 + ss] = rsum;
    }
    __syncthreads();
    for (int e = tid; e < DQ * DQ; e += NTH) {
      int r = e >> 7, c = e & 127;
      int tt = r >> 6, ss = c >> 6;
      float cv = (tt == 0) ? ((ss == 0) ? cpl00 : cpl01) : ((ss == 0) ? cpl10 : cpl11);
      float norm = cv / fmaxf(rs[r * 2 + ss], 1e-6f);
      float a = Wm[r * LDP + c] * norm;
      if (r == c) a += 1.0f - damping;
      Wm[r * LDP + c] = a;
    }
    __syncthreads();

    // ---- m = A m ----
    if (tid < DQ) {
      float s = 0.0f;
      const float* arow = Wm + tid * LDP;
      for (int k = 0; k < DQ; k++) s = fmaf(arow[k], mv[k], s);
      yv[tid] = s;
    }
    __syncthreads();
    if (tid < DQ) mv[tid] = yv[tid];
    __syncthreads();

    // ---- T = A P -> Tg ----
    {
      const int cg = tid & 15, rg = tid >> 4;
      const int c0 = cg * 8, r0 = rg * 8;
      float acc[8][8];
      #pragma unroll
      for (int i = 0; i < 8; i++)
        #pragma unroll
        for (int j = 0; j < 8; j++) acc[i][j] = 0.0f;
      for (int k = 0; k < DQ; k += 4) {
        float av[8][4];
        #pragma unroll
        for (int i = 0; i < 8; i++) {
          float4 a4 = *(const float4*)&Wm[(r0 + i) * LDP + k];
          av[i][0] = a4.x; av[i][1] = a4.y; av[i][2] = a4.z; av[i][3] = a4.w;
        }
        #pragma unroll
        for (int kk = 0; kk < 4; kk++) {
          float4 p0 = *(const float4*)&Pm[(k + kk) * LDP + c0];
          float4 p1 = *(const float4*)&Pm[(k + kk) * LDP + c0 + 4];
          float pp[8] = {p0.x, p0.y, p0.z, p0.w, p1.x, p1.y, p1.z, p1.w};
          #pragma unroll
          for (int i = 0; i < 8; i++)
            #pragma unroll
            for (int j = 0; j < 8; j++) acc[i][j] = fmaf(av[i][kk], pp[j], acc[i][j]);
        }
      }
      #pragma unroll
      for (int i = 0; i < 8; i++) {
        *(float4*)&Tg[(r0 + i) * DQ + c0]     = make_float4(acc[i][0], acc[i][1], acc[i][2], acc[i][3]);
        *(float4*)&Tg[(r0 + i) * DQ + c0 + 4] = make_float4(acc[i][4], acc[i][5], acc[i][6], acc[i][7]);
      }
    }
    __syncthreads();

    // ---- P = T A^T + q2 I ----
    {
      const int cg = tid & 15, rg = tid >> 4;
      const int c0 = cg * 8, r0 = rg * 8;
      float acc[8][8];
      #pragma unroll
      for (int i = 0; i < 8; i++)
        #pragma unroll
        for (int j = 0; j < 8; j++) acc[i][j] = 0.0f;
      for (int k = 0; k < DQ; k += 4) {
        float tvv[8][4];
        #pragma unroll
        for (int i = 0; i < 8; i++) {
          float4 t4 = *(const float4*)&Tg[(r0 + i) * DQ + k];
          tvv[i][0] = t4.x; tvv[i][1] = t4.y; tvv[i][2] = t4.z; tvv[i][3] = t4.w;
        }
        float avv[8][4];
        #pragma unroll
        for (int j = 0; j < 8; j++) {
          float4 a4 = *(const float4*)&Wm[(c0 + j) * LDP + k];
          avv[j][0] = a4.x; avv[j][1] = a4.y; avv[j][2] = a4.z; avv[j][3] = a4.w;
        }
        #pragma unroll
        for (int kk = 0; kk < 4; kk++)
          #pragma unroll
          for (int i = 0; i < 8; i++)
            #pragma unroll
            for (int j = 0; j < 8; j++) acc[i][j] = fmaf(tvv[i][kk], avv[j][kk], acc[i][j]);
      }
      #pragma unroll
      for (int i = 0; i < 8; i++)
        #pragma unroll
        for (int j = 0; j < 8; j++)
          Pm[(r0 + i) * LDP + c0 + j] = acc[i][j] + ((r0 + i == c0 + j) ? q2 : 0.0f);
    }
    __syncthreads();

    kf_update(zt, r2, Pm, Wm, gtmp, mv, vv, yv, xv, mdiag, red, Tg, nll);
  }

  if (tid == 0) nll_out[b] = nll;
}

extern "C" __global__ void ide_finalize(const float* __restrict__ part,
                                        float* __restrict__ out) {
  if (threadIdx.x == 0) {
    float s = 0.0f;
    for (int i = 0; i < BQ; i++) s += part[i];
    out[0] = s * (1.0f / BQ);
  }
}

extern "C" void kernel_launch(void* const* d_in, const int* in_sizes, int n_in,
                              void* d_out, int out_size, void* d_ws, size_t ws_size,
                              hipStream_t stream) {
  (void)in_sizes; (void)n_in; (void)out_size; (void)ws_size;
  const float* z_seq        = (const float*)d_in[0];
  const float* site_lon     = (const float*)d_in[1];
  const float* site_lat     = (const float*)d_in[2];
  const float* mu_seq       = (const float*)d_in[3];
  const float* sigma_seq    = (const float*)d_in[4];
  const float* log_q        = (const float*)d_in[5];
  const float* log_r        = (const float*)d_in[6];
  const float* log_p0       = (const float*)d_in[7];
  const float* log_damp     = (const float*)d_in[8];
  const float* init_mean    = (const float*)d_in[9];
  const float* coupling_raw = (const float*)d_in[10];
  float* ws = (float*)d_ws;
  float* out = (float*)d_out;

  const size_t smem_bytes = (size_t)SMEM_FLOATS * sizeof(float);
  hipFuncSetAttribute((const void*)ide_kf_kernel,
                      hipFuncAttributeMaxDynamicSharedMemorySize,
                      (int)smem_bytes);

  hipLaunchKernelGGL(ide_kf_kernel, dim3(BQ), dim3(NTH), smem_bytes, stream,
                     z_seq, site_lon, site_lat, mu_seq, sigma_seq,
                     log_q, log_r, log_p0, log_damp, init_mean, coupling_raw,
                     ws);
  hipLaunchKernelGGL(ide_finalize, dim3(1), dim3(64), 0, stream,
                     ws + (size_t)BQ * DQ * DQ, out);
}

// Round 2
// 23196.600 us; speedup vs baseline: 1.2986x; 1.2986x over previous
//
#include <hip/hip_runtime.h>
#include <math.h>

// IDE state-space Kalman filter, MI355X (gfx950). Round 2:
// - 512 threads/block (8 waves/CU), 4x8 register tiles
// - all matmuls LDS-resident, conflict-free access (row-op broadcast,
//   streamed op contiguous 256B across 16 lanes; A-transpose folded into
//   the T=A*P write-back)
// - no global temp round-trip; triangular halves skipped in update matmuls

#define SQ 64
#define DQ 128
#define TQ 128
#define BQ 16
#define LDP 132           // padded LDS row stride (floats); 132*4B = 16B-aligned rows
#define NTH 512
#define LOG2PI 1.8378770664093454f

#define SMEM_FLOATS 37152

__device__ __forceinline__ float block_reduce_sum(float v, float* red) {
  #pragma unroll
  for (int off = 32; off > 0; off >>= 1) v += __shfl_down(v, off);
  const int tid = threadIdx.x;
  if ((tid & 63) == 0) red[tid >> 6] = v;
  __syncthreads();
  v = 0.0f;
  #pragma unroll
  for (int w = 0; w < NTH / 64; w++) v += red[w];
  __syncthreads();
  return v;
}

// Measurement update: nll += term, m += P*Sinv*v, P = r2 * Sinv * P.
__device__ void kf_update(const float* __restrict__ zt, float r2,
                          float* Pm, float* Wm, float* gtmp,
                          float* mv, float* vv, float* yv, float* xv,
                          float* mdiag, float* red, float& nll) {
  const int tid = threadIdx.x;
  const int lane = tid & 63;
  const int cg = tid & 15, rg = tid >> 4;
  const int r0 = rg * 4, cL = cg * 4, cR = 64 + cg * 4;

  if (tid < DQ) vv[tid] = zt[tid] - mv[tid];
  for (int e = tid; e < (DQ * LDP) / 4; e += NTH)
    ((float4*)Wm)[e] = ((const float4*)Pm)[e];
  __syncthreads();
  if (tid < DQ) Wm[tid * LDP + tid] += r2;
  __syncthreads();

  // ---- blocked Cholesky (lower), NB=16 ----
  #pragma unroll 1
  for (int kb = 0; kb < 8; kb++) {
    const int b0 = kb * 16;
    // (a) 16x16 diagonal chol: wave 0, register-resident, shfl-based
    if (tid < 64) {
      float* Wd = Wm + b0 * LDP + b0;
      float a[16];
      if (lane < 16) {
        const float4* rp = (const float4*)(Wd + lane * LDP);
        float4 q0 = rp[0], q1 = rp[1], q2v = rp[2], q3 = rp[3];
        a[0]=q0.x; a[1]=q0.y; a[2]=q0.z; a[3]=q0.w;
        a[4]=q1.x; a[5]=q1.y; a[6]=q1.z; a[7]=q1.w;
        a[8]=q2v.x; a[9]=q2v.y; a[10]=q2v.z; a[11]=q2v.w;
        a[12]=q3.x; a[13]=q3.y; a[14]=q3.z; a[15]=q3.w;
      } else {
        #pragma unroll
        for (int i = 0; i < 16; i++) a[i] = 1.0f;
      }
      #pragma unroll
      for (int j = 0; j < 16; j++) {
        float dj  = __shfl(a[j], j);
        float ljj = sqrtf(dj);
        float inv = 1.0f / ljj;
        float lij = a[j] * inv;
        a[j] = (lane == j) ? ljj : lij;
        #pragma unroll
        for (int l = j + 1; l < 16; l++) {
          float llj = __shfl(a[j], l);
          a[l] = fmaf(-lij, llj, a[l]);
        }
      }
      if (lane < 16) {
        float4* rp = (float4*)(Wd + lane * LDP);
        rp[0] = make_float4(a[0], a[1], a[2], a[3]);
        rp[1] = make_float4(a[4], a[5], a[6], a[7]);
        rp[2] = make_float4(a[8], a[9], a[10], a[11]);
        rp[3] = make_float4(a[12], a[13], a[14], a[15]);
      }
    }
    __syncthreads();
    if (kb == 7) break;
    const int base = b0 + 16;
    const int nbelow = DQ - base;
    // (b) panel triangular solve: one thread per row below
    if (tid < nbelow) {
      const int r = base + tid;
      const float* Ld = Wm + b0 * LDP + b0;
      float* wrow = Wm + r * LDP + b0;
      float x[16];
      #pragma unroll
      for (int jj = 0; jj < 16; jj++) {
        float s = wrow[jj];
        #pragma unroll
        for (int l = 0; l < 16; l++) { if (l < jj) s = fmaf(-x[l], Ld[jj * LDP + l], s); }
        x[jj] = s / Ld[jj * LDP + jj];
      }
      #pragma unroll
      for (int jj = 0; jj < 16; jj++) wrow[jj] = x[jj];
    }
    __syncthreads();
    // (c) trailing update by 16x16 blocks (lower only), 2 blocks in parallel
    {
      const int z = tid >> 8;
      const int t8 = tid & 255;
      const int mrow = t8 >> 4, mcol = t8 & 15;
      const int mb = 7 - kb;
      int cnt = 0;
      for (int bi = 0; bi < mb; bi++) {
        for (int bj = 0; bj <= bi; bj++) {
          if ((cnt & 1) == z && (bi > bj || mrow >= mcol)) {
            const int i = base + bi * 16 + mrow;
            const int j = base + bj * 16 + mcol;
            const float* pi = Wm + i * LDP + b0;
            const float* pj = Wm + j * LDP + b0;
            float s = 0.0f;
            #pragma unroll
            for (int l = 0; l < 16; l++) s = fmaf(pi[l], pj[l], s);
            Wm[i * LDP + j] -= s;
          }
          cnt++;
        }
      }
    }
    __syncthreads();
  }

  float ldv = (tid < DQ) ? logf(Wm[tid * LDP + tid]) : 0.0f;
  float logdet = 2.0f * block_reduce_sum(ldv, red);

  // ---- blocked inverse of L; M = L^-1 stored transposed in strict upper of
  // Wm (M[r][c] at Wm[c*LDP+r], r>c), diagonal in mdiag. L stays intact. ----
  if (tid < DQ) {
    const int blk = tid >> 4, col = tid & 15;
    const int bb = blk * 16;
    const float* Lb = Wm + bb * LDP + bb;
    float x[16];
    #pragma unroll
    for (int i = 0; i < 16; i++) {
      float s = (i == col) ? 1.0f : 0.0f;
      #pragma unroll
      for (int k = 0; k < 16; k++) { if (k < i) s = fmaf(-Lb[i * LDP + k], x[k], s); }
      float val = s / Lb[i * LDP + i];
      x[i] = (i < col) ? 0.0f : val;
      if (i == col) mdiag[tid] = val;
      if (i > col) Wm[(bb + col) * LDP + (bb + i)] = val;
    }
  }
  __syncthreads();
  // d=1..7: M_IJ = -M_II * (sum_{K=J..I-1} L_IK M_KJ); nb split across halves
  #pragma unroll 1
  for (int d = 1; d < 8; d++) {
    const int z = tid >> 8;
    const int t8 = tid & 255;
    const int i16 = t8 >> 4, j16 = t8 & 15;
    for (int nb = z; nb + d < 8; nb += 2) {
      const int J = nb, I = nb + d;
      const float* Lrow = Wm + (I * 16 + i16) * LDP;
      float g = Lrow[J * 16 + j16] * mdiag[J * 16 + j16];
      for (int k = j16 + 1; k < 16; k++)
        g = fmaf(Lrow[J * 16 + k], Wm[(J * 16 + j16) * LDP + (J * 16 + k)], g);
      for (int K = J + 1; K < I; K++) {
        #pragma unroll
        for (int k = 0; k < 16; k++)
          g = fmaf(Lrow[K * 16 + k], Wm[(J * 16 + j16) * LDP + (K * 16 + k)], g);
      }
      gtmp[nb * 256 + t8] = g;
    }
    __syncthreads();
    for (int nb = z; nb + d < 8; nb += 2) {
      const int J = nb, I = nb + d;
      const float* gb = gtmp + nb * 256;
      float s = mdiag[I * 16 + i16] * gb[i16 * 16 + j16];
      for (int k = 0; k < i16; k++)
        s = fmaf(Wm[(I * 16 + k) * LDP + (I * 16 + i16)], gb[k * 16 + j16], s);
      Wm[(J * 16 + j16) * LDP + (I * 16 + i16)] = -s;
    }
    __syncthreads();
  }

  // ---- y = M v ; quad = |y|^2 ; xv = M^T y = Sinv v ; m += P xv ----
  if (tid < DQ) {
    float s = mdiag[tid] * vv[tid];
    for (int k = 0; k < tid; k++) s = fmaf(Wm[k * LDP + tid], vv[k], s);
    yv[tid] = s;
  }
  __syncthreads();
  float qv = (tid < DQ) ? yv[tid] * yv[tid] : 0.0f;
  float quad = block_reduce_sum(qv, red);
  if (tid < DQ) {
    float s = mdiag[tid] * yv[tid];
    for (int k = tid + 1; k < DQ; k++) s = fmaf(Wm[tid * LDP + k], yv[k], s);
    xv[tid] = s;
  }
  __syncthreads();
  // m += P xv (partials across 4 column quarters)
  {
    const int r = tid >> 2, q = tid & 3;
    const float* prow = Pm + r * LDP + q * 32;
    const float* xq = xv + q * 32;
    float s = 0.0f;
    #pragma unroll
    for (int k = 0; k < 32; k++) s = fmaf(prow[k], xq[k], s);
    gtmp[r * 4 + q] = s;
  }
  __syncthreads();
  if (tid < DQ)
    mv[tid] += gtmp[4 * tid] + gtmp[4 * tid + 1] + gtmp[4 * tid + 2] + gtmp[4 * tid + 3];
  nll += 0.5f * (quad + logdet + (float)DQ * LOG2PI);

  // ---- Y = M * P (triangular: k <= row), into registers ----
  float acc[4][8];
  #pragma unroll
  for (int i = 0; i < 4; i++)
    #pragma unroll
    for (int j = 0; j < 8; j++) acc[i][j] = 0.0f;
  for (int s = 0; s < rg; s++) {
    const int k = s * 4;
    float cv[4][4];
    #pragma unroll
    for (int kk = 0; kk < 4; kk++) {
      float4 c4 = *(const float4*)&Wm[(k + kk) * LDP + r0];
      cv[kk][0] = c4.x; cv[kk][1] = c4.y; cv[kk][2] = c4.z; cv[kk][3] = c4.w;
    }
    #pragma unroll
    for (int kk = 0; kk < 4; kk++) {
      float4 pL = *(const float4*)&Pm[(k + kk) * LDP + cL];
      float4 pR = *(const float4*)&Pm[(k + kk) * LDP + cR];
      float pp[8] = {pL.x, pL.y, pL.z, pL.w, pR.x, pR.y, pR.z, pR.w};
      #pragma unroll
      for (int i = 0; i < 4; i++)
        #pragma unroll
        for (int j = 0; j < 8; j++) acc[i][j] = fmaf(cv[kk][i], pp[j], acc[i][j]);
    }
  }
  #pragma unroll
  for (int kk = 0; kk < 4; kk++) {
    float4 pL = *(const float4*)&Pm[(r0 + kk) * LDP + cL];
    float4 pR = *(const float4*)&Pm[(r0 + kk) * LDP + cR];
    float pp[8] = {pL.x, pL.y, pL.z, pL.w, pR.x, pR.y, pR.z, pR.w};
    #pragma unroll
    for (int i = 0; i < 4; i++) {
      float coef = (kk < i) ? Wm[(r0 + kk) * LDP + r0 + i]
                 : ((kk == i) ? mdiag[r0 + i] : 0.0f);
      #pragma unroll
      for (int j = 0; j < 8; j++) acc[i][j] = fmaf(coef, pp[j], acc[i][j]);
    }
  }
  __syncthreads();
  #pragma unroll
  for (int i = 0; i < 4; i++) {
    *(float4*)&Pm[(r0 + i) * LDP + cL] = make_float4(acc[i][0], acc[i][1], acc[i][2], acc[i][3]);
    *(float4*)&Pm[(r0 + i) * LDP + cR] = make_float4(acc[i][4], acc[i][5], acc[i][6], acc[i][7]);
  }
  __syncthreads();

  // ---- P = r2 * (M^T * Y) (triangular: k >= row) ----
  #pragma unroll
  for (int i = 0; i < 4; i++)
    #pragma unroll
    for (int j = 0; j < 8; j++) acc[i][j] = 0.0f;
  #pragma unroll
  for (int kk = 0; kk < 4; kk++) {
    float4 pL = *(const float4*)&Pm[(r0 + kk) * LDP + cL];
    float4 pR = *(const float4*)&Pm[(r0 + kk) * LDP + cR];
    float pp[8] = {pL.x, pL.y, pL.z, pL.w, pR.x, pR.y, pR.z, pR.w};
    #pragma unroll
    for (int i = 0; i < 4; i++) {
      float coef = (kk > i) ? Wm[(r0 + i) * LDP + r0 + kk]
                 : ((kk == i) ? mdiag[r0 + i] : 0.0f);
      #pragma unroll
      for (int j = 0; j < 8; j++) acc[i][j] = fmaf(coef, pp[j], acc[i][j]);
    }
  }
  for (int k = r0 + 4; k < DQ; k += 4) {
    float av[4][4];
    #pragma unroll
    for (int i = 0; i < 4; i++) {
      float4 a4 = *(const float4*)&Wm[(r0 + i) * LDP + k];
      av[i][0] = a4.x; av[i][1] = a4.y; av[i][2] = a4.z; av[i][3] = a4.w;
    }
    #pragma unroll
    for (int kk = 0; kk < 4; kk++) {
      float4 pL = *(const float4*)&Pm[(k + kk) * LDP + cL];
      float4 pR = *(const float4*)&Pm[(k + kk) * LDP + cR];
      float pp[8] = {pL.x, pL.y, pL.z, pL.w, pR.x, pR.y, pR.z, pR.w};
      #pragma unroll
      for (int i = 0; i < 4; i++)
        #pragma unroll
        for (int j = 0; j < 8; j++) acc[i][j] = fmaf(av[i][kk], pp[j], acc[i][j]);
    }
  }
  __syncthreads();
  #pragma unroll
  for (int i = 0; i < 4; i++) {
    *(float4*)&Pm[(r0 + i) * LDP + cL] =
        make_float4(r2 * acc[i][0], r2 * acc[i][1], r2 * acc[i][2], r2 * acc[i][3]);
    *(float4*)&Pm[(r0 + i) * LDP + cR] =
        make_float4(r2 * acc[i][4], r2 * acc[i][5], r2 * acc[i][6], r2 * acc[i][7]);
  }
  __syncthreads();
}

extern "C" __global__ __launch_bounds__(NTH, 2)
void ide_kf_kernel(const float* __restrict__ z_seq,
                   const float* __restrict__ site_lon,
                   const float* __restrict__ site_lat,
                   const float* __restrict__ mu_seq,
                   const float* __restrict__ sigma_seq,
                   const float* __restrict__ log_q,
                   const float* __restrict__ log_r,
                   const float* __restrict__ log_p0,
                   const float* __restrict__ log_damp,
                   const float* __restrict__ init_mean,
                   const float* __restrict__ coupling_raw,
                   float* __restrict__ ws) {
  extern __shared__ float smem[];
  float* Pm     = smem;                  // 128*132
  float* Wm     = Pm + DQ * LDP;         // 128*132
  float* gtmp   = Wm + DQ * LDP;         // 2048
  float* coords = gtmp + 2048;           // 128
  float* mv     = coords + 128;          // 128
  float* vv     = mv + DQ;               // 128
  float* yv     = vv + DQ;               // 128
  float* xv     = yv + DQ;               // 128
  float* mdiag  = xv + DQ;               // 128
  float* rs2    = mdiag + DQ;            // 512
  float* tsb    = rs2 + 512;             // 24
  float* red    = tsb + 24;              // 8

  const int tid = threadIdx.x;
  const int b = blockIdx.x;
  float* nll_out = ws;

  const float r2 = expf(2.0f * log_r[0]);
  const float q2 = expf(2.0f * log_q[0]);
  const float p0sq = expf(2.0f * log_p0[0]);
  const float damping = expf(log_damp[0]);
  const float cpl00 = 1.0f + 0.25f * tanhf(coupling_raw[0]);
  const float cpl01 = 0.25f * tanhf(coupling_raw[1]);
  const float cpl10 = 0.25f * tanhf(coupling_raw[2]);
  const float cpl11 = 1.0f + 0.25f * tanhf(coupling_raw[3]);

  const int cg = tid & 15, rg = tid >> 4;
  const int r0 = rg * 4, cL = cg * 4, cR = 64 + cg * 4;

  // ---- lon/lat projection ----
  float myLon = (tid < SQ) ? site_lon[tid] : 0.0f;
  float myLat = (tid < SQ) ? site_lat[tid] : 0.0f;
  float lat0 = block_reduce_sum(myLat, red) * (1.0f / 64.0f);
  float lon0 = block_reduce_sum(myLon, red) * (1.0f / 64.0f);
  if (tid < SQ) {
    const float km = 111.32f;
    float cs = cosf(lat0 * 0.017453292519943295f);
    coords[2 * tid]     = (myLon - lon0) * (km * cs);
    coords[2 * tid + 1] = (myLat - lat0) * km;
  }
  __syncthreads();
  float dsum = 0.0f, dcnt = 0.0f;
  for (int idx = tid; idx < SQ * SQ; idx += NTH) {
    int i = idx >> 6, j = idx & 63;
    float dx = coords[2 * i] - coords[2 * j];
    float dy = coords[2 * i + 1] - coords[2 * j + 1];
    float d = sqrtf(dx * dx + dy * dy + 1e-12f);
    dsum += d;
    if (d > 1e-6f) dcnt += 1.0f;
  }
  dsum = block_reduce_sum(dsum, red);
  dcnt = block_reduce_sum(dcnt, red);
  float scale = dsum / fmaxf(dcnt, 1.0f);
  float sdiv = 1.0f / fmaxf(scale, 1e-6f);
  if (tid < SQ) { coords[2 * tid] *= sdiv; coords[2 * tid + 1] *= sdiv; }

  // ---- init m, P; first measurement update (t=0) ----
  for (int e = tid; e < (DQ * LDP) / 4; e += NTH)
    ((float4*)Pm)[e] = make_float4(0.0f, 0.0f, 0.0f, 0.0f);
  __syncthreads();
  if (tid < DQ) { Pm[tid * LDP + tid] = p0sq; mv[tid] = init_mean[tid]; }
  __syncthreads();

  float nll = 0.0f;
  kf_update(z_seq + ((size_t)b * TQ) * DQ, r2, Pm, Wm, gtmp, mv, vv, yv, xv,
            mdiag, red, nll);

  // ---- time scan ----
  #pragma unroll 1
  for (int t = 1; t < TQ; t++) {
    const float* mu_t = mu_seq + ((size_t)b * (TQ - 1) + (t - 1)) * 4;
    const float* sg_t = sigma_seq + ((size_t)b * (TQ - 1) + (t - 1)) * 16;
    const float* zt = z_seq + ((size_t)b * TQ + t) * DQ;

    // per-(t,s) Gaussian parameters
    if (tid < 4) {
      const int tt = tid >> 1, ss = tid & 1;
      float m0v = mu_t[0], m1v = mu_t[1], m2v = mu_t[2], m3v = mu_t[3];
      float dmx, dmy, c00, c01, c11;
      if (tt == 0 && ss == 0) {
        dmx = m0v; dmy = m1v;
        c00 = sg_t[0];
        c01 = 0.5f * (sg_t[1] + sg_t[4]);
        c11 = sg_t[5];
      } else if (tt == 1 && ss == 1) {
        dmx = m2v; dmy = m3v;
        c00 = sg_t[10];
        c01 = 0.5f * (sg_t[11] + sg_t[14]);
        c11 = sg_t[15];
      } else {
        dmx = 0.5f * (m0v + m2v); dmy = 0.5f * (m1v + m3v);
        float s00 = sg_t[0];
        float s02 = 0.5f * (sg_t[2] + sg_t[8]);
        float s22 = sg_t[10];
        float s01 = 0.5f * (sg_t[1] + sg_t[4]);
        float s03 = 0.5f * (sg_t[3] + sg_t[12]);
        float s21 = 0.5f * (sg_t[9] + sg_t[6]);
        float s23 = 0.5f * (sg_t[11] + sg_t[14]);
        float s11 = sg_t[5];
        float s13 = 0.5f * (sg_t[7] + sg_t[13]);
        float s33 = sg_t[15];
        c00 = 0.25f * (s00 + s02 + s02 + s22);
        c01 = 0.25f * (s01 + s03 + s21 + s23);
        c11 = 0.25f * (s11 + s13 + s13 + s33);
      }
      float D00 = 1.0001f + 2.0f * c00;
      float D01 = 2.0f * c01;
      float D11 = 1.0001f + 2.0f * c11;
      float det = D00 * D11 - D01 * D01;
      float inv = 1.0f / det;
      tsb[tid * 6 + 0] = dmx;
      tsb[tid * 6 + 1] = dmy;
      tsb[tid * 6 + 2] = D11 * inv;
      tsb[tid * 6 + 3] = -D01 * inv;
      tsb[tid * 6 + 4] = D00 * inv;
      tsb[tid * 6 + 5] = logf(det);
    }
    __syncthreads();

    // ---- build A into Wm: 512 threads, each (row, col-half, quarter) ----
    {
      const int r = tid >> 2, sub = tid & 3;
      const int ss = sub >> 1, jh = sub & 1, tt = r >> 6, i = r & 63;
      const float* tp = tsb + (tt * 2 + ss) * 6;
      float dmx = tp[0], dmy = tp[1], d00 = tp[2], d01 = tp[3], d11 = tp[4], ldts = tp[5];
      float cix = coords[2 * i], ciy = coords[2 * i + 1];
      float rsum = 0.0f;
      float* wrow = Wm + r * LDP + ss * 64 + jh * 32;
      const float* cj = coords + jh * 64;
      for (int j0 = 0; j0 < 32; j0 += 4) {
        float kv[4];
        #pragma unroll
        for (int u = 0; u < 4; u++) {
          float dx = cix - cj[2 * (j0 + u)] - dmx;
          float dy = ciy - cj[2 * (j0 + u) + 1] - dmy;
          float qf = d00 * dx * dx + 2.0f * d01 * dx * dy + d11 * dy * dy;
          kv[u] = expf(-0.5f * (qf + ldts));
          rsum += kv[u];
        }
        *(float4*)&wrow[j0] = make_float4(kv[0], kv[1], kv[2], kv[3]);
      }
      rs2[r * 4 + ss * 2 + jh] = rsum;
    }
    __syncthreads();
    for (int e = tid; e < DQ * DQ; e += NTH) {
      int r = e >> 7, c = e & 127;
      int tt = r >> 6, ss = c >> 6;
      float cv = (tt == 0) ? ((ss == 0) ? cpl00 : cpl01) : ((ss == 0) ? cpl10 : cpl11);
      float rsum = rs2[r * 4 + ss * 2] + rs2[r * 4 + ss * 2 + 1];
      float norm = cv / fmaxf(rsum, 1e-6f);
      float a = Wm[r * LDP + c] * norm;
      if (r == c) a += 1.0f - damping;
      Wm[r * LDP + c] = a;
    }
    __syncthreads();

    // ---- m = A m (partials over 4 quarters) ----
    {
      const int r = tid >> 2, q = tid & 3;
      const float* arow = Wm + r * LDP + q * 32;
      const float* mq = mv + q * 32;
      float s = 0.0f;
      #pragma unroll
      for (int k = 0; k < 32; k++) s = fmaf(arow[k], mq[k], s);
      gtmp[r * 4 + q] = s;
    }
    __syncthreads();
    float newm = 0.0f;
    if (tid < DQ)
      newm = gtmp[4 * tid] + gtmp[4 * tid + 1] + gtmp[4 * tid + 2] + gtmp[4 * tid + 3];
    __syncthreads();
    if (tid < DQ) mv[tid] = newm;

    // ---- T = A P, written TRANSPOSED into Pm ----
    {
      float acc[4][8];
      #pragma unroll
      for (int i = 0; i < 4; i++)
        #pragma unroll
        for (int j = 0; j < 8; j++) acc[i][j] = 0.0f;
      for (int k = 0; k < DQ; k += 4) {
        float av[4][4];
        #pragma unroll
        for (int i = 0; i < 4; i++) {
          float4 a4 = *(const float4*)&Wm[(r0 + i) * LDP + k];
          av[i][0] = a4.x; av[i][1] = a4.y; av[i][2] = a4.z; av[i][3] = a4.w;
        }
        #pragma unroll
        for (int kk = 0; kk < 4; kk++) {
          float4 pL = *(const float4*)&Pm[(k + kk) * LDP + cL];
          float4 pR = *(const float4*)&Pm[(k + kk) * LDP + cR];
          float pp[8] = {pL.x, pL.y, pL.z, pL.w, pR.x, pR.y, pR.z, pR.w};
          #pragma unroll
          for (int i = 0; i < 4; i++)
            #pragma unroll
            for (int j = 0; j < 8; j++) acc[i][j] = fmaf(av[i][kk], pp[j], acc[i][j]);
        }
      }
      __syncthreads();
      // Tt[c][r0..r0+3] = column vector (acc[0..3][j]) -> contiguous float4
      #pragma unroll
      for (int j = 0; j < 4; j++)
        *(float4*)&Pm[(cL + j) * LDP + r0] =
            make_float4(acc[0][j], acc[1][j], acc[2][j], acc[3][j]);
      #pragma unroll
      for (int j = 0; j < 4; j++)
        *(float4*)&Pm[(cR + j) * LDP + r0] =
            make_float4(acc[0][4 + j], acc[1][4 + j], acc[2][4 + j], acc[3][4 + j]);
      __syncthreads();

      // ---- P' = A * Tt + q2 I  (= (T A^T)^T = T A^T by symmetry) ----
      #pragma unroll
      for (int i = 0; i < 4; i++)
        #pragma unroll
        for (int j = 0; j < 8; j++) acc[i][j] = 0.0f;
      for (int k = 0; k < DQ; k += 4) {
        float av[4][4];
        #pragma unroll
        for (int i = 0; i < 4; i++) {
          float4 a4 = *(const float4*)&Wm[(r0 + i) * LDP + k];
          av[i][0] = a4.x; av[i][1] = a4.y; av[i][2] = a4.z; av[i][3] = a4.w;
        }
        #pragma unroll
        for (int kk = 0; kk < 4; kk++) {
          float4 pL = *(const float4*)&Pm[(k + kk) * LDP + cL];
          float4 pR = *(const float4*)&Pm[(k + kk) * LDP + cR];
          float pp[8] = {pL.x, pL.y, pL.z, pL.w, pR.x, pR.y, pR.z, pR.w};
          #pragma unroll
          for (int i = 0; i < 4; i++)
            #pragma unroll
            for (int j = 0; j < 8; j++) acc[i][j] = fmaf(av[i][kk], pp[j], acc[i][j]);
        }
      }
      __syncthreads();
      #pragma unroll
      for (int i = 0; i < 4; i++) {
        const int rr = r0 + i;
        float4 vL = make_float4(acc[i][0], acc[i][1], acc[i][2], acc[i][3]);
        float4 vR = make_float4(acc[i][4], acc[i][5], acc[i][6], acc[i][7]);
        if (rr >= cL && rr < cL + 4) {
          if (rr == cL)     vL.x += q2;
          if (rr == cL + 1) vL.y += q2;
          if (rr == cL + 2) vL.z += q2;
          if (rr == cL + 3) vL.w += q2;
        }
        if (rr >= cR && rr < cR + 4) {
          if (rr == cR)     vR.x += q2;
          if (rr == cR + 1) vR.y += q2;
          if (rr == cR + 2) vR.z += q2;
          if (rr == cR + 3) vR.w += q2;
        }
        *(float4*)&Pm[rr * LDP + cL] = vL;
        *(float4*)&Pm[rr * LDP + cR] = vR;
      }
      __syncthreads();
    }

    kf_update(zt, r2, Pm, Wm, gtmp, mv, vv, yv, xv, mdiag, red, nll);
  }

  if (tid == 0) nll_out[b] = nll;
}

extern "C" __global__ void ide_finalize(const float* __restrict__ part,
                                        float* __restrict__ out) {
  if (threadIdx.x == 0) {
    float s = 0.0f;
    for (int i = 0; i < BQ; i++) s += part[i];
    out[0] = s * (1.0f / BQ);
  }
}

extern "C" void kernel_launch(void* const* d_in, const int* in_sizes, int n_in,
                              void* d_out, int out_size, void* d_ws, size_t ws_size,
                              hipStream_t stream) {
  (void)in_sizes; (void)n_in; (void)out_size; (void)ws_size;
  const float* z_seq        = (const float*)d_in[0];
  const float* site_lon     = (const float*)d_in[1];
  const float* site_lat     = (const float*)d_in[2];
  const float* mu_seq       = (const float*)d_in[3];
  const float* sigma_seq    = (const float*)d_in[4];
  const float* log_q        = (const float*)d_in[5];
  const float* log_r        = (const float*)d_in[6];
  const float* log_p0       = (const float*)d_in[7];
  const float* log_damp     = (const float*)d_in[8];
  const float* init_mean    = (const float*)d_in[9];
  const float* coupling_raw = (const float*)d_in[10];
  float* ws = (float*)d_ws;
  float* out = (float*)d_out;

  const size_t smem_bytes = (size_t)SMEM_FLOATS * sizeof(float);
  hipFuncSetAttribute((const void*)ide_kf_kernel,
                      hipFuncAttributeMaxDynamicSharedMemorySize,
                      (int)smem_bytes);

  hipLaunchKernelGGL(ide_kf_kernel, dim3(BQ), dim3(NTH), smem_bytes, stream,
                     z_seq, site_lon, site_lat, mu_seq, sigma_seq,
                     log_q, log_r, log_p0, log_damp, init_mean, coupling_raw,
                     ws);
  hipLaunchKernelGGL(ide_finalize, dim3(1), dim3(64), 0, stream, ws, out);
}

// Round 3
// 23033.797 us; speedup vs baseline: 1.3077x; 1.0071x over previous
//
#include <hip/hip_runtime.h>
#include <math.h>

// IDE state-space Kalman filter, MI355X (gfx950). Round 3:
// - 1024 threads/block (16 waves/CU, 4 per SIMD) for latency hiding
// - matmuls: 4x8 register tiles, k-parity split across thread halves,
//   two-phase write/add merge (no extra LDS, disjoint elements)
// - Cholesky panel solve turned into a parallel small matmul via per-block
//   16x16 diagonal inverses computed inside the chol loop (trinv d=0 removed)
// - 4-way splits for chol trailing / trinv / GEMVs

#define SQ 64
#define DQ 128
#define TQ 128
#define BQ 16
#define LDP 132           // padded LDS row stride (floats); rows 16B-aligned
#define NTH 1024
#define LOG2PI 1.8378770664093454f

#define SMEM_FLOATS 37672

__device__ __forceinline__ float block_reduce_sum(float v, float* red) {
  #pragma unroll
  for (int off = 32; off > 0; off >>= 1) v += __shfl_down(v, off);
  const int tid = threadIdx.x;
  if ((tid & 63) == 0) red[tid >> 6] = v;
  __syncthreads();
  v = 0.0f;
  #pragma unroll
  for (int w = 0; w < NTH / 64; w++) v += red[w];
  __syncthreads();
  return v;
}

// Measurement update: nll += term, m += P*Sinv*v, P = r2 * Sinv * P.
__device__ void kf_update(const float* __restrict__ zt, float r2,
                          float* Pm, float* Wm, float* gtmp,
                          float* mv, float* vv, float* yv, float* xv,
                          float* mdiag, float* red, float& nll) {
  const int tid = threadIdx.x;
  const int lane = tid & 63;
  const int z  = tid >> 9;          // matmul half (k-parity)
  const int t9 = tid & 511;
  const int cg = t9 & 15, rg = t9 >> 4;
  const int r0 = rg * 4, cL = cg * 4, cR = 64 + cg * 4;

  if (tid < DQ) vv[tid] = zt[tid] - mv[tid];
  for (int e = tid; e < (DQ * LDP) / 4; e += NTH)
    ((float4*)Wm)[e] = ((const float4*)Pm)[e];
  __syncthreads();
  if (tid < DQ) Wm[tid * LDP + tid] += r2;
  __syncthreads();

  // ---- blocked Cholesky (lower), NB=16, with inline diagonal-block inverse ----
  #pragma unroll 1
  for (int kb = 0; kb < 8; kb++) {
    const int b0 = kb * 16;
    // (a) 16x16 diagonal chol: wave 0, register-resident, shfl-based
    if (tid < 64) {
      float* Wd = Wm + b0 * LDP + b0;
      float a[16];
      if (lane < 16) {
        const float4* rp = (const float4*)(Wd + lane * LDP);
        float4 q0 = rp[0], q1 = rp[1], q2v = rp[2], q3 = rp[3];
        a[0]=q0.x; a[1]=q0.y; a[2]=q0.z; a[3]=q0.w;
        a[4]=q1.x; a[5]=q1.y; a[6]=q1.z; a[7]=q1.w;
        a[8]=q2v.x; a[9]=q2v.y; a[10]=q2v.z; a[11]=q2v.w;
        a[12]=q3.x; a[13]=q3.y; a[14]=q3.z; a[15]=q3.w;
      } else {
        #pragma unroll
        for (int i = 0; i < 16; i++) a[i] = 1.0f;
      }
      #pragma unroll
      for (int j = 0; j < 16; j++) {
        float dj  = __shfl(a[j], j);
        float ljj = sqrtf(dj);
        float inv = 1.0f / ljj;
        float lij = a[j] * inv;
        a[j] = (lane == j) ? ljj : lij;
        #pragma unroll
        for (int l = j + 1; l < 16; l++) {
          float llj = __shfl(a[j], l);
          a[l] = fmaf(-lij, llj, a[l]);
        }
      }
      if (lane < 16) {
        float4* rp = (float4*)(Wd + lane * LDP);
        rp[0] = make_float4(a[0], a[1], a[2], a[3]);
        rp[1] = make_float4(a[4], a[5], a[6], a[7]);
        rp[2] = make_float4(a[8], a[9], a[10], a[11]);
        rp[3] = make_float4(a[12], a[13], a[14], a[15]);
      }
      // (a2) invert the just-factored 16x16 lower triangle (same wave, no
      // barrier needed). Result: diag -> mdiag, strict part transposed into
      // the upper triangle of this diagonal block.
      if (lane < 16) {
        const int col = lane;
        const float* Lb = Wm + b0 * LDP + b0;
        float x[16];
        #pragma unroll
        for (int i = 0; i < 16; i++) {
          float s = (i == col) ? 1.0f : 0.0f;
          #pragma unroll
          for (int k = 0; k < 16; k++) { if (k < i) s = fmaf(-Lb[i * LDP + k], x[k], s); }
          float val = s / Lb[i * LDP + i];
          x[i] = (i < col) ? 0.0f : val;
          if (i == col) mdiag[b0 + col] = val;
          if (i > col) Wm[(b0 + col) * LDP + (b0 + i)] = val;
        }
      }
    }
    __syncthreads();
    if (kb == 7) break;
    const int base = b0 + 16;
    const int nbelow = DQ - base;
    // (b) panel: L_panel = W_panel * Ldiag^{-T} — fully parallel small matmul
    {
      const int rr = tid >> 4, j = tid & 15;
      const int rA = base + rr, rB = rA + 64;
      const float md = mdiag[b0 + j];
      float outA = 0.0f, outB = 0.0f;
      const bool vA = rr < nbelow;
      const bool vB = rr + 64 < nbelow;
      if (vA) {
        const float* wr = Wm + rA * LDP + b0;
        float s = 0.0f;
        for (int l = 0; l < j; l++)
          s = fmaf(wr[l], Wm[(b0 + l) * LDP + (b0 + j)], s);
        outA = fmaf(wr[j], md, s);
      }
      if (vB) {
        const float* wr = Wm + rB * LDP + b0;
        float s = 0.0f;
        for (int l = 0; l < j; l++)
          s = fmaf(wr[l], Wm[(b0 + l) * LDP + (b0 + j)], s);
        outB = fmaf(wr[j], md, s);
      }
      __syncthreads();
      if (vA) Wm[rA * LDP + b0 + j] = outA;
      if (vB) Wm[rB * LDP + b0 + j] = outB;
    }
    __syncthreads();
    // (c) trailing update by 16x16 blocks (lower only), 4-way split
    {
      const int z4 = tid >> 8;
      const int t8 = tid & 255;
      const int mrow = t8 >> 4, mcol = t8 & 15;
      const int mb = 7 - kb;
      int cnt = 0;
      for (int bi = 0; bi < mb; bi++) {
        for (int bj = 0; bj <= bi; bj++) {
          if ((cnt & 3) == z4 && (bi > bj || mrow >= mcol)) {
            const int i = base + bi * 16 + mrow;
            const int j = base + bj * 16 + mcol;
            const float* pi = Wm + i * LDP + b0;
            const float* pj = Wm + j * LDP + b0;
            float s = 0.0f;
            #pragma unroll
            for (int l = 0; l < 16; l++) s = fmaf(pi[l], pj[l], s);
            Wm[i * LDP + j] -= s;
          }
          cnt++;
        }
      }
    }
    __syncthreads();
  }

  float ldv = (tid < DQ) ? logf(mdiag[tid]) : 0.0f;
  float logdet = -2.0f * block_reduce_sum(ldv, red);

  // ---- off-diagonal blocks of M = L^-1 (transposed-upper storage) ----
  #pragma unroll 1
  for (int d = 1; d < 8; d++) {
    const int z4 = tid >> 8;
    const int t8 = tid & 255;
    const int i16 = t8 >> 4, j16 = t8 & 15;
    for (int nb = z4; nb + d < 8; nb += 4) {
      const int J = nb, I = nb + d;
      const float* Lrow = Wm + (I * 16 + i16) * LDP;
      float g = Lrow[J * 16 + j16] * mdiag[J * 16 + j16];
      for (int k = j16 + 1; k < 16; k++)
        g = fmaf(Lrow[J * 16 + k], Wm[(J * 16 + j16) * LDP + (J * 16 + k)], g);
      for (int K = J + 1; K < I; K++) {
        #pragma unroll
        for (int k = 0; k < 16; k++)
          g = fmaf(Lrow[K * 16 + k], Wm[(J * 16 + j16) * LDP + (K * 16 + k)], g);
      }
      gtmp[nb * 256 + t8] = g;
    }
    __syncthreads();
    for (int nb = z4; nb + d < 8; nb += 4) {
      const int J = nb, I = nb + d;
      const float* gb = gtmp + nb * 256;
      float s = mdiag[I * 16 + i16] * gb[i16 * 16 + j16];
      for (int k = 0; k < i16; k++)
        s = fmaf(Wm[(I * 16 + k) * LDP + (I * 16 + i16)], gb[k * 16 + j16], s);
      Wm[(J * 16 + j16) * LDP + (I * 16 + i16)] = -s;
    }
    __syncthreads();
  }

  // ---- y = M v (4-way k-split) ----
  if (tid < 512) {
    const int i = tid & 127, q = tid >> 7;
    const int k0 = q * 32;
    const int k1 = min(k0 + 32, i);
    float s = 0.0f;
    for (int k = k0; k < k1; k++) s = fmaf(Wm[k * LDP + i], vv[k], s);
    if (q == (i >> 5)) s = fmaf(mdiag[i], vv[i], s);
    gtmp[i * 4 + q] = s;
  }
  __syncthreads();
  if (tid < DQ)
    yv[tid] = gtmp[4 * tid] + gtmp[4 * tid + 1] + gtmp[4 * tid + 2] + gtmp[4 * tid + 3];
  __syncthreads();
  float qv = (tid < DQ) ? yv[tid] * yv[tid] : 0.0f;
  float quad = block_reduce_sum(qv, red);
  // ---- x = M^T y (4-way k-split) ----
  if (tid < 512) {
    const int i = tid & 127, q = tid >> 7;
    const int k0 = max(q * 32, i + 1);
    const int k1 = q * 32 + 32;
    float s = 0.0f;
    for (int k = k0; k < k1; k++) s = fmaf(Wm[i * LDP + k], yv[k], s);
    if (q == (i >> 5)) s = fmaf(mdiag[i], yv[i], s);
    gtmp[i * 4 + q] = s;
  }
  __syncthreads();
  if (tid < DQ)
    xv[tid] = gtmp[4 * tid] + gtmp[4 * tid + 1] + gtmp[4 * tid + 2] + gtmp[4 * tid + 3];
  __syncthreads();
  // ---- m += P x (8-way k-split) ----
  {
    const int r = tid >> 3, q8 = tid & 7;
    const float* prow = Pm + r * LDP + q8 * 16;
    const float* xq = xv + q8 * 16;
    float s = 0.0f;
    #pragma unroll
    for (int k = 0; k < 16; k++) s = fmaf(prow[k], xq[k], s);
    gtmp[r * 8 + q8] = s;
  }
  __syncthreads();
  if (tid < DQ) {
    float s = mv[tid];
    #pragma unroll
    for (int u = 0; u < 8; u++) s += gtmp[8 * tid + u];
    mv[tid] = s;
  }
  nll += 0.5f * (quad + logdet + (float)DQ * LOG2PI);

  // ---- Y = M * P (triangular: k <= row), z-split partial sums ----
  float acc[4][8];
  #pragma unroll
  for (int i = 0; i < 4; i++)
    #pragma unroll
    for (int j = 0; j < 8; j++) acc[i][j] = 0.0f;
  if (z == 0) {
    // boundary chunk k = r0..r0+3
    #pragma unroll
    for (int kk = 0; kk < 4; kk++) {
      float4 pL = *(const float4*)&Pm[(r0 + kk) * LDP + cL];
      float4 pR = *(const float4*)&Pm[(r0 + kk) * LDP + cR];
      float pp[8] = {pL.x, pL.y, pL.z, pL.w, pR.x, pR.y, pR.z, pR.w};
      #pragma unroll
      for (int i = 0; i < 4; i++) {
        float coef = (kk < i) ? Wm[(r0 + kk) * LDP + r0 + i]
                   : ((kk == i) ? mdiag[r0 + i] : 0.0f);
        #pragma unroll
        for (int j = 0; j < 8; j++) acc[i][j] = fmaf(coef, pp[j], acc[i][j]);
      }
    }
  }
  for (int c = z; c < rg; c += 2) {
    const int k = c * 4;
    float cv[4][4];
    #pragma unroll
    for (int kk = 0; kk < 4; kk++) {
      float4 c4 = *(const float4*)&Wm[(k + kk) * LDP + r0];
      cv[kk][0] = c4.x; cv[kk][1] = c4.y; cv[kk][2] = c4.z; cv[kk][3] = c4.w;
    }
    #pragma unroll
    for (int kk = 0; kk < 4; kk++) {
      float4 pL = *(const float4*)&Pm[(k + kk) * LDP + cL];
      float4 pR = *(const float4*)&Pm[(k + kk) * LDP + cR];
      float pp[8] = {pL.x, pL.y, pL.z, pL.w, pR.x, pR.y, pR.z, pR.w};
      #pragma unroll
      for (int i = 0; i < 4; i++)
        #pragma unroll
        for (int j = 0; j < 8; j++) acc[i][j] = fmaf(cv[kk][i], pp[j], acc[i][j]);
    }
  }
  __syncthreads();
  if (z == 0) {
    #pragma unroll
    for (int i = 0; i < 4; i++) {
      *(float4*)&Pm[(r0 + i) * LDP + cL] = make_float4(acc[i][0], acc[i][1], acc[i][2], acc[i][3]);
      *(float4*)&Pm[(r0 + i) * LDP + cR] = make_float4(acc[i][4], acc[i][5], acc[i][6], acc[i][7]);
    }
  }
  __syncthreads();
  if (z == 1) {
    #pragma unroll
    for (int i = 0; i < 4; i++) {
      float4 vL = *(float4*)&Pm[(r0 + i) * LDP + cL];
      float4 vR = *(float4*)&Pm[(r0 + i) * LDP + cR];
      vL.x += acc[i][0]; vL.y += acc[i][1]; vL.z += acc[i][2]; vL.w += acc[i][3];
      vR.x += acc[i][4]; vR.y += acc[i][5]; vR.z += acc[i][6]; vR.w += acc[i][7];
      *(float4*)&Pm[(r0 + i) * LDP + cL] = vL;
      *(float4*)&Pm[(r0 + i) * LDP + cR] = vR;
    }
  }
  __syncthreads();

  // ---- P = r2 * (M^T * Y) (triangular: k >= row), z-split ----
  #pragma unroll
  for (int i = 0; i < 4; i++)
    #pragma unroll
    for (int j = 0; j < 8; j++) acc[i][j] = 0.0f;
  if (z == 0) {
    #pragma unroll
    for (int kk = 0; kk < 4; kk++) {
      float4 pL = *(const float4*)&Pm[(r0 + kk) * LDP + cL];
      float4 pR = *(const float4*)&Pm[(r0 + kk) * LDP + cR];
      float pp[8] = {pL.x, pL.y, pL.z, pL.w, pR.x, pR.y, pR.z, pR.w};
      #pragma unroll
      for (int i = 0; i < 4; i++) {
        float coef = (kk > i) ? Wm[(r0 + i) * LDP + r0 + kk]
                   : ((kk == i) ? mdiag[r0 + i] : 0.0f);
        #pragma unroll
        for (int j = 0; j < 8; j++) acc[i][j] = fmaf(coef, pp[j], acc[i][j]);
      }
    }
  }
  {
    const int cstart = rg + 1;
    for (int c = cstart + ((cstart ^ z) & 1); c < 32; c += 2) {
      const int k = c * 4;
      float av[4][4];
      #pragma unroll
      for (int i = 0; i < 4; i++) {
        float4 a4 = *(const float4*)&Wm[(r0 + i) * LDP + k];
        av[i][0] = a4.x; av[i][1] = a4.y; av[i][2] = a4.z; av[i][3] = a4.w;
      }
      #pragma unroll
      for (int kk = 0; kk < 4; kk++) {
        float4 pL = *(const float4*)&Pm[(k + kk) * LDP + cL];
        float4 pR = *(const float4*)&Pm[(k + kk) * LDP + cR];
        float pp[8] = {pL.x, pL.y, pL.z, pL.w, pR.x, pR.y, pR.z, pR.w};
        #pragma unroll
        for (int i = 0; i < 4; i++)
          #pragma unroll
          for (int j = 0; j < 8; j++) acc[i][j] = fmaf(av[i][kk], pp[j], acc[i][j]);
      }
    }
  }
  __syncthreads();
  if (z == 0) {
    #pragma unroll
    for (int i = 0; i < 4; i++) {
      *(float4*)&Pm[(r0 + i) * LDP + cL] =
          make_float4(r2 * acc[i][0], r2 * acc[i][1], r2 * acc[i][2], r2 * acc[i][3]);
      *(float4*)&Pm[(r0 + i) * LDP + cR] =
          make_float4(r2 * acc[i][4], r2 * acc[i][5], r2 * acc[i][6], r2 * acc[i][7]);
    }
  }
  __syncthreads();
  if (z == 1) {
    #pragma unroll
    for (int i = 0; i < 4; i++) {
      float4 vL = *(float4*)&Pm[(r0 + i) * LDP + cL];
      float4 vR = *(float4*)&Pm[(r0 + i) * LDP + cR];
      vL.x += r2 * acc[i][0]; vL.y += r2 * acc[i][1];
      vL.z += r2 * acc[i][2]; vL.w += r2 * acc[i][3];
      vR.x += r2 * acc[i][4]; vR.y += r2 * acc[i][5];
      vR.z += r2 * acc[i][6]; vR.w += r2 * acc[i][7];
      *(float4*)&Pm[(r0 + i) * LDP + cL] = vL;
      *(float4*)&Pm[(r0 + i) * LDP + cR] = vR;
    }
  }
  __syncthreads();
}

extern "C" __global__ __launch_bounds__(NTH, 4)
void ide_kf_kernel(const float* __restrict__ z_seq,
                   const float* __restrict__ site_lon,
                   const float* __restrict__ site_lat,
                   const float* __restrict__ mu_seq,
                   const float* __restrict__ sigma_seq,
                   const float* __restrict__ log_q,
                   const float* __restrict__ log_r,
                   const float* __restrict__ log_p0,
                   const float* __restrict__ log_damp,
                   const float* __restrict__ init_mean,
                   const float* __restrict__ coupling_raw,
                   float* __restrict__ ws) {
  extern __shared__ float smem[];
  float* Pm     = smem;                  // 128*132
  float* Wm     = Pm + DQ * LDP;         // 128*132
  float* gtmp   = Wm + DQ * LDP;         // 2048
  float* coords = gtmp + 2048;           // 128
  float* mv     = coords + 128;          // 128
  float* vv     = mv + DQ;               // 128
  float* yv     = vv + DQ;               // 128
  float* xv     = yv + DQ;               // 128
  float* mdiag  = xv + DQ;               // 128
  float* rs2    = mdiag + DQ;            // 1024
  float* tsb    = rs2 + 1024;            // 24
  float* red    = tsb + 24;              // 16

  const int tid = threadIdx.x;
  const int b = blockIdx.x;
  float* nll_out = ws;

  const float r2 = expf(2.0f * log_r[0]);
  const float q2 = expf(2.0f * log_q[0]);
  const float p0sq = expf(2.0f * log_p0[0]);
  const float damping = expf(log_damp[0]);
  const float cpl00 = 1.0f + 0.25f * tanhf(coupling_raw[0]);
  const float cpl01 = 0.25f * tanhf(coupling_raw[1]);
  const float cpl10 = 0.25f * tanhf(coupling_raw[2]);
  const float cpl11 = 1.0f + 0.25f * tanhf(coupling_raw[3]);

  const int z  = tid >> 9;
  const int t9 = tid & 511;
  const int cg = t9 & 15, rg = t9 >> 4;
  const int r0 = rg * 4, cL = cg * 4, cR = 64 + cg * 4;

  // ---- lon/lat projection ----
  float myLon = (tid < SQ) ? site_lon[tid] : 0.0f;
  float myLat = (tid < SQ) ? site_lat[tid] : 0.0f;
  float lat0 = block_reduce_sum(myLat, red) * (1.0f / 64.0f);
  float lon0 = block_reduce_sum(myLon, red) * (1.0f / 64.0f);
  if (tid < SQ) {
    const float km = 111.32f;
    float cs = cosf(lat0 * 0.017453292519943295f);
    coords[2 * tid]     = (myLon - lon0) * (km * cs);
    coords[2 * tid + 1] = (myLat - lat0) * km;
  }
  __syncthreads();
  float dsum = 0.0f, dcnt = 0.0f;
  for (int idx = tid; idx < SQ * SQ; idx += NTH) {
    int i = idx >> 6, j = idx & 63;
    float dx = coords[2 * i] - coords[2 * j];
    float dy = coords[2 * i + 1] - coords[2 * j + 1];
    float d = sqrtf(dx * dx + dy * dy + 1e-12f);
    dsum += d;
    if (d > 1e-6f) dcnt += 1.0f;
  }
  dsum = block_reduce_sum(dsum, red);
  dcnt = block_reduce_sum(dcnt, red);
  float scale = dsum / fmaxf(dcnt, 1.0f);
  float sdiv = 1.0f / fmaxf(scale, 1e-6f);
  if (tid < SQ) { coords[2 * tid] *= sdiv; coords[2 * tid + 1] *= sdiv; }

  // ---- init m, P; first measurement update (t=0) ----
  for (int e = tid; e < (DQ * LDP) / 4; e += NTH)
    ((float4*)Pm)[e] = make_float4(0.0f, 0.0f, 0.0f, 0.0f);
  __syncthreads();
  if (tid < DQ) { Pm[tid * LDP + tid] = p0sq; mv[tid] = init_mean[tid]; }
  __syncthreads();

  float nll = 0.0f;
  kf_update(z_seq + ((size_t)b * TQ) * DQ, r2, Pm, Wm, gtmp, mv, vv, yv, xv,
            mdiag, red, nll);

  // ---- time scan ----
  #pragma unroll 1
  for (int t = 1; t < TQ; t++) {
    const float* mu_t = mu_seq + ((size_t)b * (TQ - 1) + (t - 1)) * 4;
    const float* sg_t = sigma_seq + ((size_t)b * (TQ - 1) + (t - 1)) * 16;
    const float* zt = z_seq + ((size_t)b * TQ + t) * DQ;

    // per-(t,s) Gaussian parameters
    if (tid < 4) {
      const int tt = tid >> 1, ss = tid & 1;
      float m0v = mu_t[0], m1v = mu_t[1], m2v = mu_t[2], m3v = mu_t[3];
      float dmx, dmy, c00, c01, c11;
      if (tt == 0 && ss == 0) {
        dmx = m0v; dmy = m1v;
        c00 = sg_t[0];
        c01 = 0.5f * (sg_t[1] + sg_t[4]);
        c11 = sg_t[5];
      } else if (tt == 1 && ss == 1) {
        dmx = m2v; dmy = m3v;
        c00 = sg_t[10];
        c01 = 0.5f * (sg_t[11] + sg_t[14]);
        c11 = sg_t[15];
      } else {
        dmx = 0.5f * (m0v + m2v); dmy = 0.5f * (m1v + m3v);
        float s00 = sg_t[0];
        float s02 = 0.5f * (sg_t[2] + sg_t[8]);
        float s22 = sg_t[10];
        float s01 = 0.5f * (sg_t[1] + sg_t[4]);
        float s03 = 0.5f * (sg_t[3] + sg_t[12]);
        float s21 = 0.5f * (sg_t[9] + sg_t[6]);
        float s23 = 0.5f * (sg_t[11] + sg_t[14]);
        float s11 = sg_t[5];
        float s13 = 0.5f * (sg_t[7] + sg_t[13]);
        float s33 = sg_t[15];
        c00 = 0.25f * (s00 + s02 + s02 + s22);
        c01 = 0.25f * (s01 + s03 + s21 + s23);
        c11 = 0.25f * (s11 + s13 + s13 + s33);
      }
      float D00 = 1.0001f + 2.0f * c00;
      float D01 = 2.0f * c01;
      float D11 = 1.0001f + 2.0f * c11;
      float det = D00 * D11 - D01 * D01;
      float inv = 1.0f / det;
      tsb[tid * 6 + 0] = dmx;
      tsb[tid * 6 + 1] = dmy;
      tsb[tid * 6 + 2] = D11 * inv;
      tsb[tid * 6 + 3] = -D01 * inv;
      tsb[tid * 6 + 4] = D00 * inv;
      tsb[tid * 6 + 5] = logf(det);
    }
    __syncthreads();

    // ---- build A into Wm: 1024 threads = (row, col-half, col-quarter16) ----
    {
      const int r = tid >> 3, sub = tid & 7;
      const int ss = sub >> 2, jq = sub & 3, tt = r >> 6, i = r & 63;
      const float* tp = tsb + (tt * 2 + ss) * 6;
      float dmx = tp[0], dmy = tp[1], d00 = tp[2], d01 = tp[3], d11 = tp[4], ldts = tp[5];
      float cix = coords[2 * i], ciy = coords[2 * i + 1];
      float rsum = 0.0f;
      float* wrow = Wm + r * LDP + ss * 64 + jq * 16;
      const float* cj = coords + jq * 32;
      for (int j0 = 0; j0 < 16; j0 += 4) {
        float kv[4];
        #pragma unroll
        for (int u = 0; u < 4; u++) {
          float dx = cix - cj[2 * (j0 + u)] - dmx;
          float dy = ciy - cj[2 * (j0 + u) + 1] - dmy;
          float qf = d00 * dx * dx + 2.0f * d01 * dx * dy + d11 * dy * dy;
          kv[u] = expf(-0.5f * (qf + ldts));
          rsum += kv[u];
        }
        *(float4*)&wrow[j0] = make_float4(kv[0], kv[1], kv[2], kv[3]);
      }
      rs2[r * 8 + ss * 4 + jq] = rsum;
    }
    __syncthreads();
    for (int e = tid; e < DQ * DQ; e += NTH) {
      int r = e >> 7, c = e & 127;
      int tt = r >> 6, ss = c >> 6;
      float cv = (tt == 0) ? ((ss == 0) ? cpl00 : cpl01) : ((ss == 0) ? cpl10 : cpl11);
      float rsum = rs2[r * 8 + ss * 4] + rs2[r * 8 + ss * 4 + 1]
                 + rs2[r * 8 + ss * 4 + 2] + rs2[r * 8 + ss * 4 + 3];
      float norm = cv / fmaxf(rsum, 1e-6f);
      float a = Wm[r * LDP + c] * norm;
      if (r == c) a += 1.0f - damping;
      Wm[r * LDP + c] = a;
    }
    __syncthreads();

    // ---- m = A m (8-way k-split) ----
    {
      const int r = tid >> 3, q8 = tid & 7;
      const float* arow = Wm + r * LDP + q8 * 16;
      const float* mq = mv + q8 * 16;
      float s = 0.0f;
      #pragma unroll
      for (int k = 0; k < 16; k++) s = fmaf(arow[k], mq[k], s);
      gtmp[r * 8 + q8] = s;
    }
    __syncthreads();
    float newm = 0.0f;
    if (tid < DQ) {
      #pragma unroll
      for (int u = 0; u < 8; u++) newm += gtmp[8 * tid + u];
    }
    __syncthreads();
    if (tid < DQ) mv[tid] = newm;

    // ---- T = A P, written TRANSPOSED into Pm (z-split k-parity) ----
    {
      float acc[4][8];
      #pragma unroll
      for (int i = 0; i < 4; i++)
        #pragma unroll
        for (int j = 0; j < 8; j++) acc[i][j] = 0.0f;
      for (int c = z; c < 32; c += 2) {
        const int k = c * 4;
        float av[4][4];
        #pragma unroll
        for (int i = 0; i < 4; i++) {
          float4 a4 = *(const float4*)&Wm[(r0 + i) * LDP + k];
          av[i][0] = a4.x; av[i][1] = a4.y; av[i][2] = a4.z; av[i][3] = a4.w;
        }
        #pragma unroll
        for (int kk = 0; kk < 4; kk++) {
          float4 pL = *(const float4*)&Pm[(k + kk) * LDP + cL];
          float4 pR = *(const float4*)&Pm[(k + kk) * LDP + cR];
          float pp[8] = {pL.x, pL.y, pL.z, pL.w, pR.x, pR.y, pR.z, pR.w};
          #pragma unroll
          for (int i = 0; i < 4; i++)
            #pragma unroll
            for (int j = 0; j < 8; j++) acc[i][j] = fmaf(av[i][kk], pp[j], acc[i][j]);
        }
      }
      __syncthreads();
      if (z == 0) {
        #pragma unroll
        for (int j = 0; j < 4; j++)
          *(float4*)&Pm[(cL + j) * LDP + r0] =
              make_float4(acc[0][j], acc[1][j], acc[2][j], acc[3][j]);
        #pragma unroll
        for (int j = 0; j < 4; j++)
          *(float4*)&Pm[(cR + j) * LDP + r0] =
              make_float4(acc[0][4 + j], acc[1][4 + j], acc[2][4 + j], acc[3][4 + j]);
      }
      __syncthreads();
      if (z == 1) {
        #pragma unroll
        for (int j = 0; j < 4; j++) {
          float4 v = *(float4*)&Pm[(cL + j) * LDP + r0];
          v.x += acc[0][j]; v.y += acc[1][j]; v.z += acc[2][j]; v.w += acc[3][j];
          *(float4*)&Pm[(cL + j) * LDP + r0] = v;
        }
        #pragma unroll
        for (int j = 0; j < 4; j++) {
          float4 v = *(float4*)&Pm[(cR + j) * LDP + r0];
          v.x += acc[0][4 + j]; v.y += acc[1][4 + j];
          v.z += acc[2][4 + j]; v.w += acc[3][4 + j];
          *(float4*)&Pm[(cR + j) * LDP + r0] = v;
        }
      }
      __syncthreads();

      // ---- P' = A * Tt + q2 I (z-split k-parity) ----
      #pragma unroll
      for (int i = 0; i < 4; i++)
        #pragma unroll
        for (int j = 0; j < 8; j++) acc[i][j] = 0.0f;
      for (int c = z; c < 32; c += 2) {
        const int k = c * 4;
        float av[4][4];
        #pragma unroll
        for (int i = 0; i < 4; i++) {
          float4 a4 = *(const float4*)&Wm[(r0 + i) * LDP + k];
          av[i][0] = a4.x; av[i][1] = a4.y; av[i][2] = a4.z; av[i][3] = a4.w;
        }
        #pragma unroll
        for (int kk = 0; kk < 4; kk++) {
          float4 pL = *(const float4*)&Pm[(k + kk) * LDP + cL];
          float4 pR = *(const float4*)&Pm[(k + kk) * LDP + cR];
          float pp[8] = {pL.x, pL.y, pL.z, pL.w, pR.x, pR.y, pR.z, pR.w};
          #pragma unroll
          for (int i = 0; i < 4; i++)
            #pragma unroll
            for (int j = 0; j < 8; j++) acc[i][j] = fmaf(av[i][kk], pp[j], acc[i][j]);
        }
      }
      __syncthreads();
      if (z == 0) {
        #pragma unroll
        for (int i = 0; i < 4; i++) {
          const int rr = r0 + i;
          float4 vL = make_float4(acc[i][0], acc[i][1], acc[i][2], acc[i][3]);
          float4 vR = make_float4(acc[i][4], acc[i][5], acc[i][6], acc[i][7]);
          if (rr >= cL && rr < cL + 4) {
            if (rr == cL)     vL.x += q2;
            if (rr == cL + 1) vL.y += q2;
            if (rr == cL + 2) vL.z += q2;
            if (rr == cL + 3) vL.w += q2;
          }
          if (rr >= cR && rr < cR + 4) {
            if (rr == cR)     vR.x += q2;
            if (rr == cR + 1) vR.y += q2;
            if (rr == cR + 2) vR.z += q2;
            if (rr == cR + 3) vR.w += q2;
          }
          *(float4*)&Pm[rr * LDP + cL] = vL;
          *(float4*)&Pm[rr * LDP + cR] = vR;
        }
      }
      __syncthreads();
      if (z == 1) {
        #pragma unroll
        for (int i = 0; i < 4; i++) {
          float4 vL = *(float4*)&Pm[(r0 + i) * LDP + cL];
          float4 vR = *(float4*)&Pm[(r0 + i) * LDP + cR];
          vL.x += acc[i][0]; vL.y += acc[i][1]; vL.z += acc[i][2]; vL.w += acc[i][3];
          vR.x += acc[i][4]; vR.y += acc[i][5]; vR.z += acc[i][6]; vR.w += acc[i][7];
          *(float4*)&Pm[(r0 + i) * LDP + cL] = vL;
          *(float4*)&Pm[(r0 + i) * LDP + cR] = vR;
        }
      }
      __syncthreads();
    }

    kf_update(zt, r2, Pm, Wm, gtmp, mv, vv, yv, xv, mdiag, red, nll);
  }

  if (tid == 0) nll_out[b] = nll;
}

extern "C" __global__ void ide_finalize(const float* __restrict__ part,
                                        float* __restrict__ out) {
  if (threadIdx.x == 0) {
    float s = 0.0f;
    for (int i = 0; i < BQ; i++) s += part[i];
    out[0] = s * (1.0f / BQ);
  }
}

extern "C" void kernel_launch(void* const* d_in, const int* in_sizes, int n_in,
                              void* d_out, int out_size, void* d_ws, size_t ws_size,
                              hipStream_t stream) {
  (void)in_sizes; (void)n_in; (void)out_size; (void)ws_size;
  const float* z_seq        = (const float*)d_in[0];
  const float* site_lon     = (const float*)d_in[1];
  const float* site_lat     = (const float*)d_in[2];
  const float* mu_seq       = (const float*)d_in[3];
  const float* sigma_seq    = (const float*)d_in[4];
  const float* log_q        = (const float*)d_in[5];
  const float* log_r        = (const float*)d_in[6];
  const float* log_p0       = (const float*)d_in[7];
  const float* log_damp     = (const float*)d_in[8];
  const float* init_mean    = (const float*)d_in[9];
  const float* coupling_raw = (const float*)d_in[10];
  float* ws = (float*)d_ws;
  float* out = (float*)d_out;

  const size_t smem_bytes = (size_t)SMEM_FLOATS * sizeof(float);
  hipFuncSetAttribute((const void*)ide_kf_kernel,
                      hipFuncAttributeMaxDynamicSharedMemorySize,
                      (int)smem_bytes);

  hipLaunchKernelGGL(ide_kf_kernel, dim3(BQ), dim3(NTH), smem_bytes, stream,
                     z_seq, site_lon, site_lat, mu_seq, sigma_seq,
                     log_q, log_r, log_p0, log_damp, init_mean, coupling_raw,
                     ws);
  hipLaunchKernelGGL(ide_finalize, dim3(1), dim3(64), 0, stream, ws, out);
}